// Round 3
// baseline (529.908 us; speedup 1.0000x reference)
//
#include <hip/hip_runtime.h>

#define NB   64
#define NH   8
#define NM   1024
#define NC   128
#define NMID 64
#define NT   256
#define ITERS 16          // 16 rows/iter x 16 iters = 256 rows per wave
#define RWS  132          // rwT row stride in shorts (66 dwords == 2 mod 32: conflict-free)

typedef short s16x8 __attribute__((ext_vector_type(8)));
typedef float f32x4 __attribute__((ext_vector_type(4)));

__device__ __forceinline__ unsigned fbits(float x){ union{float f;unsigned u;}v; v.f=x; return v.u; }
__device__ __forceinline__ float   ffrom(unsigned u){ union{unsigned u;float f;}v; v.u=u; return v.f; }

// truncate-split: hi = trunc16(x), lo = trunc16(x - hi). Exact to ~2^-16 with
// the 3-term MFMA (Ah*Bh + Al*Bh + Ah*Bl); dropped cross term ~2^-16.
__device__ __forceinline__ void cvt1(float x, short& hi, short& lo) {
    const unsigned u = fbits(x);
    hi = (short)(u >> 16);
    const float lf = x - ffrom(u & 0xffff0000u);
    lo = (short)(fbits(lf) >> 16);
}

__global__ __launch_bounds__(NT, 2)
void scatt_kernel(const float* __restrict__ query,
                  const float* __restrict__ key_feat,
                  const int*   __restrict__ att_mask,
                  const float* __restrict__ value1,
                  const float* __restrict__ value2,
                  const float* __restrict__ w_basic,
                  const float* __restrict__ b_basic,
                  const float* __restrict__ w_last,
                  const float* __restrict__ b_last,
                  const float* __restrict__ w_last2,
                  const float* __restrict__ b_last2,
                  float* __restrict__ out)
{
    const int bh   = blockIdx.x;          // 0..511
    const int b    = bh >> 3;
    const int h    = bh & 7;
    const int t    = threadIdx.x;
    const int lane = t & 63;
    const int w    = t >> 6;              // wave 0..3: owns rows [w*256, w*256+256)
    const int ln15 = lane & 15;           // A row / B col (o) index
    const int lq   = lane >> 4;           // k-quad

    __shared__ short rwT_hi[NMID * RWS];  // 16896 B  B^T hi  [o][i]
    __shared__ short rwT_lo[NMID * RWS];  // 16896 B
    __shared__ float mlds[NM];            //  4096 B  mask as float
    __shared__ float logits[NM];          //  4096 B  logit partials -> alpha
    __shared__ float poolp[4][NMID];      //  1024 B  per-wave pool partials
    __shared__ float pool_s[NMID];        //   256 B
    __shared__ float v2part[8][NC];       //  4096 B
    __shared__ float red[8];
    __shared__ float sscal[4];

    const float* kf  = key_feat + (size_t)bh * NM * NC;
    const float* v2g = value2   + (size_t)bh * NM * NC;

    // ---- preload kf iter 0 (in A-fragment layout, straight from global) ----
    float4 buf[2][8];
    {
        const float* row0 = kf + (size_t)(w * 256 + ln15) * NC;
        #pragma unroll
        for (int ks = 0; ks < 4; ++ks) {
            buf[0][2*ks]   = *(const float4*)(row0 + ks*32 + lq*8);
            buf[0][2*ks+1] = *(const float4*)(row0 + ks*32 + lq*8 + 4);
        }
    }

    // ---- mask -> LDS ----
    #pragma unroll
    for (int m = t; m < NM; m += NT) mlds[m] = (float)att_mask[b * NM + m];

    // ---- build rwT = (q (.) w_basic)^T hi/lo in LDS ----
    {
        const float* wb = w_basic + (size_t)h * NC * NMID;
        const float* qp = query + bh * NC;
        #pragma unroll 4
        for (int r = 0; r < 32; ++r) {
            const int f = r * NT + t;      // coalesced over wb; i = f>>6 wave-uniform
            const int o = f & 63;
            const int i = f >> 6;
            short hs, ls;
            cvt1(qp[i] * wb[f], hs, ls);
            rwT_hi[o * RWS + i] = hs;
            rwT_lo[o * RWS + i] = ls;
        }
    }
    __syncthreads();                      // the ONLY barrier before Phase 2

    // ---- hoist B fragments: 4 o-subtiles x 4 ksteps, hi+lo (128 VGPRs) ----
    s16x8 Bh[4][4], Bl[4][4];
    #pragma unroll
    for (int osub = 0; osub < 4; ++osub) {
        const int o = osub * 16 + ln15;
        #pragma unroll
        for (int ks = 0; ks < 4; ++ks) {
            const int off = o * RWS + ks * 32 + lq * 8;
            Bh[osub][ks] = *(const s16x8*)&rwT_hi[off];
            Bl[osub][ks] = *(const s16x8*)&rwT_lo[off];
        }
    }

    float bb[4], wl[4], pool[4];
    #pragma unroll
    for (int osub = 0; osub < 4; ++osub) {
        bb[osub] = b_basic[h * NMID + osub * 16 + ln15];
        wl[osub] = w_last[h * NMID + osub * 16 + ln15];
        pool[osub] = 0.f;
    }
    const float bl = b_last[h];

    // ---- Phase 1: barrier-free. Each wave: 16 iters x (16 rows x 64 o) ----
    #pragma unroll 2
    for (int it = 0; it < ITERS; ++it) {
        const int cb = it & 1;            // constant after unroll-2
        // prefetch next iter while computing this one (no barriers -> stays in flight)
        if (it + 1 < ITERS) {
            const float* nrow = kf + (size_t)(w * 256 + (it + 1) * 16 + ln15) * NC;
            #pragma unroll
            for (int ks = 0; ks < 4; ++ks) {
                buf[cb ^ 1][2*ks]   = *(const float4*)(nrow + ks*32 + lq*8);
                buf[cb ^ 1][2*ks+1] = *(const float4*)(nrow + ks*32 + lq*8 + 4);
            }
        }

        // convert current buffer to A fragments (hi/lo truncate-split)
        s16x8 Ah[4], Al[4];
        #pragma unroll
        for (int ks = 0; ks < 4; ++ks) {
            const float4 a = buf[cb][2*ks];
            const float4 c = buf[cb][2*ks+1];
            short hs, ls;
            cvt1(a.x, hs, ls); Ah[ks][0] = hs; Al[ks][0] = ls;
            cvt1(a.y, hs, ls); Ah[ks][1] = hs; Al[ks][1] = ls;
            cvt1(a.z, hs, ls); Ah[ks][2] = hs; Al[ks][2] = ls;
            cvt1(a.w, hs, ls); Ah[ks][3] = hs; Al[ks][3] = ls;
            cvt1(c.x, hs, ls); Ah[ks][4] = hs; Al[ks][4] = ls;
            cvt1(c.y, hs, ls); Ah[ks][5] = hs; Al[ks][5] = ls;
            cvt1(c.z, hs, ls); Ah[ks][6] = hs; Al[ks][6] = ls;
            cvt1(c.w, hs, ls); Ah[ks][7] = hs; Al[ks][7] = ls;
        }

        f32x4 acc0 = {0.f,0.f,0.f,0.f}, acc1 = {0.f,0.f,0.f,0.f};
        f32x4 acc2 = {0.f,0.f,0.f,0.f}, acc3 = {0.f,0.f,0.f,0.f};
        #pragma unroll
        for (int ks = 0; ks < 4; ++ks) {
            acc0 = __builtin_amdgcn_mfma_f32_16x16x32_bf16(Ah[ks], Bh[0][ks], acc0, 0, 0, 0);
            acc1 = __builtin_amdgcn_mfma_f32_16x16x32_bf16(Ah[ks], Bh[1][ks], acc1, 0, 0, 0);
            acc2 = __builtin_amdgcn_mfma_f32_16x16x32_bf16(Ah[ks], Bh[2][ks], acc2, 0, 0, 0);
            acc3 = __builtin_amdgcn_mfma_f32_16x16x32_bf16(Ah[ks], Bh[3][ks], acc3, 0, 0, 0);
            acc0 = __builtin_amdgcn_mfma_f32_16x16x32_bf16(Al[ks], Bh[0][ks], acc0, 0, 0, 0);
            acc1 = __builtin_amdgcn_mfma_f32_16x16x32_bf16(Al[ks], Bh[1][ks], acc1, 0, 0, 0);
            acc2 = __builtin_amdgcn_mfma_f32_16x16x32_bf16(Al[ks], Bh[2][ks], acc2, 0, 0, 0);
            acc3 = __builtin_amdgcn_mfma_f32_16x16x32_bf16(Al[ks], Bh[3][ks], acc3, 0, 0, 0);
            acc0 = __builtin_amdgcn_mfma_f32_16x16x32_bf16(Ah[ks], Bl[0][ks], acc0, 0, 0, 0);
            acc1 = __builtin_amdgcn_mfma_f32_16x16x32_bf16(Ah[ks], Bl[1][ks], acc1, 0, 0, 0);
            acc2 = __builtin_amdgcn_mfma_f32_16x16x32_bf16(Ah[ks], Bl[2][ks], acc2, 0, 0, 0);
            acc3 = __builtin_amdgcn_mfma_f32_16x16x32_bf16(Ah[ks], Bl[3][ks], acc3, 0, 0, 0);
        }

        // epilogue: relu + pool + logit. D layout: o = osub*16 + (lane&15), row = lq*4+reg
        const int mbase = w * 256 + it * 16 + lq * 4;
        #pragma unroll
        for (int reg = 0; reg < 4; ++reg) {
            const float mv = mlds[mbase + reg];
            const float y0 = fmaxf(acc0[reg] + bb[0], 0.f);
            const float y1 = fmaxf(acc1[reg] + bb[1], 0.f);
            const float y2 = fmaxf(acc2[reg] + bb[2], 0.f);
            const float y3 = fmaxf(acc3[reg] + bb[3], 0.f);
            pool[0] = fmaf(mv, y0, pool[0]);
            pool[1] = fmaf(mv, y1, pool[1]);
            pool[2] = fmaf(mv, y2, pool[2]);
            pool[3] = fmaf(mv, y3, pool[3]);
            float c = fmaf(y0, wl[0], fmaf(y1, wl[1], fmaf(y2, wl[2], y3 * wl[3])));
            c += __shfl_xor(c, 1, 16);
            c += __shfl_xor(c, 2, 16);
            c += __shfl_xor(c, 4, 16);
            c += __shfl_xor(c, 8, 16);
            if (ln15 == 0) logits[mbase + reg] = c;   // lanes 0,16,32,48 cover lq=0..3
        }
    }

    // pool: reduce across lq groups -> per-o partials for this wave
    #pragma unroll
    for (int osub = 0; osub < 4; ++osub) {
        float p = pool[osub];
        p += __shfl_xor(p, 16, 64);
        p += __shfl_xor(p, 32, 64);
        if (lane < 16) poolp[w][osub * 16 + lane] = p;
    }
    __syncthreads();   // B1: logits + poolp complete

    // ---- Phase 2: masked softmax prep + pool finalize ----
    float lmax = -1e30f, csum = 0.f;
    #pragma unroll
    for (int m = t; m < NM; m += NT) {
        const float mv = mlds[m];
        float lg = logits[m] + bl;
        lg = (mv != 0.f) ? lg : -1e9f;
        logits[m] = lg;
        lmax = fmaxf(lmax, lg);
        csum += mv;
    }
    #pragma unroll
    for (int s = 32; s > 0; s >>= 1) {
        lmax = fmaxf(lmax, __shfl_xor(lmax, s, 64));
        csum += __shfl_xor(csum, s, 64);
    }
    if (lane == 0) { red[w] = lmax; red[4 + w] = csum; }
    __syncthreads();   // B2
    if (t == 0) {
        sscal[0] = fmaxf(fmaxf(red[0], red[1]), fmaxf(red[2], red[3]));
        sscal[2] = red[4] + red[5] + red[6] + red[7];
    }
    __syncthreads();   // B3
    const float mx  = sscal[0];
    const float cnt = sscal[2];
    if (t < NMID)
        pool_s[t] = (poolp[0][t] + poolp[1][t] + poolp[2][t] + poolp[3][t]) / cnt;
    float esum = 0.f;
    #pragma unroll
    for (int m = t; m < NM; m += NT) {
        const float e = __expf(logits[m] - mx);
        logits[m] = e;                 // unnormalized alpha
        esum += e;
    }
    #pragma unroll
    for (int s = 32; s > 0; s >>= 1) esum += __shfl_xor(esum, s, 64);
    if (lane == 0) red[w] = esum;
    __syncthreads();   // B4
    if (t == 0) sscal[1] = red[0] + red[1] + red[2] + red[3];
    __syncthreads();   // B5
    const float inv_sum = 1.f / sscal[1];

    // ---- Phase 3: v2 = alpha @ value2 (streaming, coalesced) ----
    const int d4 = t & 31;
    const int mg = t >> 5;
    float4 acc = make_float4(0.f, 0.f, 0.f, 0.f);
    const float4* v24 = (const float4*)v2g;
    #pragma unroll 4
    for (int m0 = 0; m0 < NM; m0 += 8) {
        const int m = m0 + mg;
        const float a = logits[m];
        const float4 v = v24[(size_t)m * 32 + d4];
        acc.x = fmaf(a, v.x, acc.x);
        acc.y = fmaf(a, v.y, acc.y);
        acc.z = fmaf(a, v.z, acc.z);
        acc.w = fmaf(a, v.w, acc.w);
    }
    ((float4*)&v2part[mg][0])[d4] = acc;
    __syncthreads();   // B6

    // ---- Phase 4: channel gate + output ----
    if (t < NC) {
        float v2d = 0.f;
        #pragma unroll
        for (int g = 0; g < 8; ++g) v2d += v2part[g][t];
        v2d *= inv_sum;
        float accd = b_last2[h * NC + t];
        const float* wl2 = w_last2 + (size_t)h * NMID * NC + t;
        #pragma unroll 8
        for (int o = 0; o < NMID; ++o)
            accd = fmaf(pool_s[o], wl2[(size_t)o * NC], accd);
        const float ach = 1.f / (1.f + __expf(-accd));
        out[bh * NC + t] = value1[bh * NC + t] * v2d * ach;
    }
}

extern "C" void kernel_launch(void* const* d_in, const int* in_sizes, int n_in,
                              void* d_out, int out_size, void* d_ws, size_t ws_size,
                              hipStream_t stream) {
    (void)in_sizes; (void)n_in; (void)out_size; (void)d_ws; (void)ws_size;
    const float* query    = (const float*)d_in[0];
    const float* key_feat = (const float*)d_in[1];
    const int*   att_mask = (const int*)d_in[2];
    const float* value1   = (const float*)d_in[3];
    const float* value2   = (const float*)d_in[4];
    const float* w_basic  = (const float*)d_in[5];
    const float* b_basic  = (const float*)d_in[6];
    const float* w_last   = (const float*)d_in[7];
    const float* b_last   = (const float*)d_in[8];
    const float* w_last2  = (const float*)d_in[9];
    const float* b_last2  = (const float*)d_in[10];
    float* outp = (float*)d_out;

    scatt_kernel<<<dim3(NB * NH), dim3(NT), 0, stream>>>(
        query, key_feat, att_mask, value1, value2,
        w_basic, b_basic, w_last, b_last, w_last2, b_last2, outp);
}